// Round 10
// baseline (272.445 us; speedup 1.0000x reference)
//
#include <hip/hip_runtime.h>

// Problem constants (fixed by setup_inputs):
//   x: [B=64, D=64, H=32, W=32] fp32   -> N = B*H*W = 65536 rows of D=64
//   codebook: [K=512, D=64] fp32
// Output layout (all fp32, concatenated flat in return order):
//   [0 .. 4194304)        quant_out [B,D,H,W]
//   [4194304]             loss
//   [4194305]             perplexity
//   [4194306 .. +65536)   encoding_indice [B, H*W] (as float)
//   [4259842 .. +32768)   index_program [B,K]
//   [4292610 .. +32768)   softmax_histogram [B,K]

#define OFF_LOSS 4194304
#define OFF_PERP 4194305
#define OFF_ENC  4194306
#define OFF_IP   4259842
#define OFF_SH   4292610

// Scores replicate the reference's fp32 expansion exactly (R6-proven):
//   t1   = fl32( ||x_r||^2 + ||e_k||^2 );  dist = fl32( t1 - 2*dot )
// argmin with lowest-k tie-break.
//
// R10: vq_main hot loop is the EXACT R6 body (120 VGPR, 20% occ, 152 us —
// best known). R7-R9's swizzle/prefetch/float4-staging variants all pushed
// VGPR to 132 (past the 128 cliff) or spilled; conflicts proved a minor tax.
// New: vq_final folded in via last-block-done (counter in out[OFF_PERP],
// threadfence handshake) — removes one dispatch + gap.
__global__ __launch_bounds__(256) void vq_main(
    const float* __restrict__ x, const float* __restrict__ cb,
    float* __restrict__ out)
{
    __shared__ float xs[64 * 64];      // xs[d*64 + r], transposed x tile
    __shared__ float csT[64 * 132];    // csT[d*132 + k] for current 128-code chunk
    __shared__ float ce2[512];         // ||e_k||^2 (fp32)
    __shared__ float sxx[64];          // ||x_r||^2 (fp32) per row
    __shared__ int   sidx[64];         // argmin code per row
    __shared__ int   s_last;

    const int t    = threadIdx.x;
    const int blk  = blockIdx.x;
    const int b    = blk >> 4;          // batch index
    const int row0 = (blk & 15) << 6;   // row offset within batch (H*W space)
    const int tr   = t >> 5;            // 0..7  (row group)
    const int tc   = t & 31;            // 0..31 (col group)

    // ---- stage x tile (coalesced: lanes sweep r for fixed d) ----
    {
        const float* xb = x + ((size_t)b << 16) + row0;   // b*D*HW
        #pragma unroll
        for (int p = 0; p < 16; ++p) {
            const int d = (p << 2) + (t >> 6);
            const int r = t & 63;
            xs[(d << 6) + r] = xb[((size_t)d << 10) + r];
        }
    }
    __syncthreads();
    // ---- ||x_r||^2 fp32, sequential fmaf over d ----
    if (t < 64) {
        float s = 0.f;
        for (int d = 0; d < 64; ++d) { const float v = xs[(d << 6) + t]; s = fmaf(v, v, s); }
        sxx[t] = s;
    }

    float acc[8][16];
    #pragma unroll
    for (int i = 0; i < 8; ++i)
        #pragma unroll
        for (int c = 0; c < 16; ++c) acc[i][c] = 0.f;

    const float4* cb4 = (const float4*)cb;

    // ---- GEMM: 4 chunks of 128 codes ----
    #pragma unroll
    for (int kc = 0; kc < 4; ++kc) {
        __syncthreads();   // csT free (prior chunk's reads done); sxx visible
        // stage csT (register transpose) + ce2 for codes [kc*128, kc*128+128)
        #pragma unroll
        for (int p = 0; p < 8; ++p) {
            const int fi = (p << 8) + t;      // float4 index in chunk, 0..2047
            const int k  = fi >> 4;           // 0..127
            const int d4 = fi & 15;           // which float4 along D
            const float4 v = cb4[(kc << 11) + fi];   // coalesced
            csT[((d4 << 2) + 0) * 132 + k] = v.x;
            csT[((d4 << 2) + 1) * 132 + k] = v.y;
            csT[((d4 << 2) + 2) * 132 + k] = v.z;
            csT[((d4 << 2) + 3) * 132 + k] = v.w;
            float pr = v.x * v.x + v.y * v.y + v.z * v.z + v.w * v.w;
            #pragma unroll
            for (int off = 1; off < 16; off <<= 1) pr += __shfl_xor(pr, off, 16);
            if ((t & 15) == 0) ce2[(kc << 7) + k] = pr;
        }
        __syncthreads();
        for (int d = 0; d < 64; ++d) {
            const float4 a0 = *(const float4*)&xs[(d << 6) + (tr << 2)];
            const float4 a1 = *(const float4*)&xs[(d << 6) + (tr << 2) + 32];
            const float4 bq = *(const float4*)&csT[d * 132 + (tc << 2)];
            const float av[8] = {a0.x, a0.y, a0.z, a0.w, a1.x, a1.y, a1.z, a1.w};
            const float bv[4] = {bq.x, bq.y, bq.z, bq.w};
            #pragma unroll
            for (int i = 0; i < 8; ++i)
                #pragma unroll
                for (int j = 0; j < 4; ++j)
                    acc[i][(kc << 2) + j] = fmaf(av[i], bv[j], acc[i][(kc << 2) + j]);
        }
    }

    // ---- epilogue: ref-exact fp32 dist; per-row argmin + softmax(-dist) ----
    float* ip  = out + OFF_IP;
    float* enc = out + OFF_ENC;
    float invz[8];

    #pragma unroll
    for (int i = 0; i < 8; ++i) {
        const int row = ((i >> 2) << 5) + (tr << 2) + (i & 3);
        const float xxr = sxx[row];
        float m = 1e30f; int bk = 0;
        #pragma unroll
        for (int c = 0; c < 16; ++c) {
            const int k = ((c >> 2) << 7) + (tc << 2) + (c & 3);   // ascending in c
            const float t1   = xxr + ce2[k];          // fp32 round @ ulp(~64)
            const float dist = t1 - 2.f * acc[i][c];  // fp32 round @ ulp(~64)
            acc[i][c] = dist;
            if (dist < m) { m = dist; bk = k; }       // strict <: lowest k kept
        }
        // lexicographic (min dist, min k) butterfly across the 32 lanes of row
        #pragma unroll
        for (int off = 1; off < 32; off <<= 1) {
            const float mo = __shfl_xor(m, off, 32);
            const int   ko = __shfl_xor(bk, off, 32);
            if (mo < m || (mo == m && ko < bk)) { m = mo; bk = ko; }
        }
        float z = 0.f;
        #pragma unroll
        for (int c = 0; c < 16; ++c) {
            const float e = __expf(m - acc[i][c]);    // softmax(-dist), shifted
            acc[i][c] = e; z += e;
        }
        #pragma unroll
        for (int off = 1; off < 32; off <<= 1) z += __shfl_xor(z, off, 32);
        invz[i] = 1.f / z;

        if (tc == 0) {
            sidx[row] = bk;
            atomicAdd(&ip[((size_t)b << 9) + bk], 1.0f);
            enc[((size_t)b << 10) + row0 + row] = (float)bk;
        }
    }

    __syncthreads();   // all csT reads done; sidx visible

    // ---- softmax histogram: block-reduce in LDS (alias csT), then global ----
    float* shist = csT;
    float* sh    = out + OFF_SH;
    shist[t] = 0.f; shist[t + 256] = 0.f;
    __syncthreads();
    #pragma unroll
    for (int c = 0; c < 16; ++c) {
        const int k = ((c >> 2) << 7) + (tc << 2) + (c & 3);
        float cs = 0.f;
        #pragma unroll
        for (int i = 0; i < 8; ++i) cs += acc[i][c] * invz[i];
        atomicAdd(&shist[k], cs);
    }
    __syncthreads();
    atomicAdd(&sh[((size_t)b << 9) + t], shist[t]);
    atomicAdd(&sh[((size_t)b << 9) + t + 256], shist[t + 256]);

    // ---- quantized output + loss partial (from sidx) ----
    const int r = t & 63;
    const int code = sidx[r];
    float lsum = 0.f;
    #pragma unroll
    for (int p = 0; p < 16; ++p) {
        const int d = (p << 2) + (t >> 6);
        const float q = cb[(code << 6) + d];
        const float diff = q - xs[(d << 6) + r];
        lsum += diff * diff;
        out[(((size_t)(b << 6) + d) << 10) + row0 + r] = q;
    }
    #pragma unroll
    for (int off = 1; off < 64; off <<= 1) lsum += __shfl_xor(lsum, off, 64);
    if ((t & 63) == 0) atomicAdd(&out[OFF_LOSS], lsum);

    // ---- last-block-done: fold the final reduction into this kernel ----
    __threadfence();                       // release: our ip/sh/loss writes
    if (t == 0) {
        const int prev = atomicAdd((int*)(out + OFF_PERP), 1);  // slot pre-zeroed
        s_last = (prev == 1023) ? 1 : 0;
    }
    __syncthreads();
    if (s_last) {
        __threadfence();                   // acquire: see all blocks' writes
        float h = 0.f;
        #pragma unroll
        for (int kk = 0; kk < 2; ++kk) {
            const int k = t + (kk << 8);
            float c0 = 0.f, c1 = 0.f, c2 = 0.f, c3 = 0.f;
            #pragma unroll
            for (int bb = 0; bb < 64; bb += 4) {
                c0 += ip[((bb + 0) << 9) + k];
                c1 += ip[((bb + 1) << 9) + k];
                c2 += ip[((bb + 2) << 9) + k];
                c3 += ip[((bb + 3) << 9) + k];
            }
            const float cnt = (c0 + c1) + (c2 + c3);
            const float pav = cnt * (1.0f / 65536.f);
            h += pav * logf(pav + 1e-10f);
        }
        #pragma unroll
        for (int off = 1; off < 64; off <<= 1) h += __shfl_xor(h, off, 64);
        if ((t & 63) == 0) sxx[t >> 6] = h;   // reuse sxx as scratch
        __syncthreads();
        if (t == 0) {
            const float H = sxx[0] + sxx[1] + sxx[2] + sxx[3];
            out[OFF_PERP] = expf(-H);
            out[OFF_LOSS] = out[OFF_LOSS] * (1.25f / 4194304.f);
        }
    }
}

extern "C" void kernel_launch(void* const* d_in, const int* in_sizes, int n_in,
                              void* d_out, int out_size, void* d_ws, size_t ws_size,
                              hipStream_t stream)
{
    const float* x  = (const float*)d_in[0];
    const float* cb = (const float*)d_in[1];
    float* out = (float*)d_out;
    (void)d_ws; (void)ws_size;

    // single memset: zero [loss, perp(counter), enc, ip, sh] = tail 131074 floats.
    hipMemsetAsync(out + OFF_LOSS, 0, (size_t)131074 * sizeof(float), stream);

    vq_main<<<1024, 256, 0, stream>>>(x, cb, out);
}

// Round 11
// 244.534 us; speedup vs baseline: 1.1141x; 1.1141x over previous
//
#include <hip/hip_runtime.h>

// Problem constants (fixed by setup_inputs):
//   x: [B=64, D=64, H=32, W=32] fp32   -> N = B*H*W = 65536 rows of D=64
//   codebook: [K=512, D=64] fp32
// Output layout (all fp32, concatenated flat in return order):
//   [0 .. 4194304)        quant_out [B,D,H,W]
//   [4194304]             loss
//   [4194305]             perplexity
//   [4194306 .. +65536)   encoding_indice [B, H*W] (as float)
//   [4259842 .. +32768)   index_program [B,K]
//   [4292610 .. +32768)   softmax_histogram [B,K]

#define OFF_LOSS 4194304
#define OFF_PERP 4194305
#define OFF_ENC  4194306
#define OFF_IP   4259842
#define OFF_SH   4292610

// Scores replicate the reference's fp32 expansion exactly (R6-proven):
//   t1   = fl32( ||x_r||^2 + ||e_k||^2 );  dist = fl32( t1 - 2*dot )
// argmin with lowest-k tie-break. All fmaf chains are source-verbatim R6
// (dot: ascending d per acc element; ce2: same expr + 16-lane xor tree;
// sxx: sequential fmaf; dist: same expr) => bit-identical scores.
//
// R11 structure: B comes from a GLOBAL transposed codebook (cbT in d_ws,
// L1/L2-resident, 4 coalesced dwordx4 per d) instead of LDS csT. The d-loop
// drops from 3 LDS insts/32 FMAs to 2 LDS insts/128 FMAs — the R6-R10
// ~152us LDS-issue bound (VALUBusy 33%) moves toward the 27us FMA floor.
// quant+loss live in a separate small kernel (gemm's epilogue would race
// with the cbT stash otherwise, and it's HBM-bound anyway).
// R10's threadfence fold removed (cost ~100us: per-block device-scope L2
// drain on non-coherent XCDs).

// ---- prep: cbT[d][k] = cb[k][d] (128 KB in d_ws) ----
__global__ __launch_bounds__(64) void vq_prep(const float* __restrict__ cb,
                                              float* __restrict__ cbT)
{
    const int k = blockIdx.x;        // 0..511
    const int d = threadIdx.x;       // 0..63
    cbT[(d << 9) + k] = cb[(k << 6) + d];
}

// ---- gemm + argmin + softmax + enc/ip/sh (no quant, no loss) ----
__global__ __launch_bounds__(256) void vq_gemm(
    const float* __restrict__ x, const float* __restrict__ cb,
    const float* __restrict__ cbT, float* __restrict__ out)
{
    __shared__ float xs[64 * 64];      // xs[d*64 + r], transposed x tile
    __shared__ float ce2[512];         // ||e_k||^2 (fp32)
    __shared__ float sxx[64];          // ||x_r||^2 (fp32) per row
    __shared__ float shist[512];       // softmax-histogram block reduce

    const int t    = threadIdx.x;
    const int blk  = blockIdx.x;
    const int b    = blk >> 4;          // batch index
    const int row0 = (blk & 15) << 6;   // row offset within batch (H*W space)
    const int tr   = t >> 5;            // 0..7  (row group)
    const int tc   = t & 31;            // 0..31 (col group)

    const float4* cb4  = (const float4*)cb;
    const float4* cbT4 = (const float4*)cbT;

    // ---- stage x tile (coalesced: lanes sweep r for fixed d) ----
    {
        const float* xb = x + ((size_t)b << 16) + row0;   // b*D*HW
        #pragma unroll
        for (int p = 0; p < 16; ++p) {
            const int d = (p << 2) + (t >> 6);
            const int r = t & 63;
            xs[(d << 6) + r] = xb[((size_t)d << 10) + r];
        }
    }

    // ---- ce2: verbatim R6 arithmetic (expr + 16-lane xor tree) ----
    #pragma unroll
    for (int kc = 0; kc < 4; ++kc) {
        #pragma unroll
        for (int p = 0; p < 8; ++p) {
            const int fi = (p << 8) + t;      // float4 index in chunk, 0..2047
            const int k  = fi >> 4;           // 0..127
            const float4 v = cb4[(kc << 11) + fi];   // coalesced
            float pr = v.x * v.x + v.y * v.y + v.z * v.z + v.w * v.w;
            #pragma unroll
            for (int off = 1; off < 16; off <<= 1) pr += __shfl_xor(pr, off, 16);
            if ((t & 15) == 0) ce2[(kc << 7) + k] = pr;
        }
    }

    __syncthreads();   // xs + ce2 visible

    // ---- ||x_r||^2 fp32, sequential fmaf over d (verbatim R6) ----
    if (t < 64) {
        float s = 0.f;
        for (int d = 0; d < 64; ++d) { const float v = xs[(d << 6) + t]; s = fmaf(v, v, s); }
        sxx[t] = s;
    }

    float acc[8][16];
    #pragma unroll
    for (int i = 0; i < 8; ++i)
        #pragma unroll
        for (int c = 0; c < 16; ++c) acc[i][c] = 0.f;

    // ---- K-loop: A from LDS (2 ds_read_b128), B from global cbT (4 dwordx4,
    //      L1-hot: all waves share row d), 128 FMAs per d.
    //      Chain per acc[i][c]: ascending d, fmaf — bit-identical to R6. ----
    #pragma unroll 1
    for (int d = 0; d < 64; ++d) {
        const float4 a0 = *(const float4*)&xs[(d << 6) + (tr << 2)];
        const float4 a1 = *(const float4*)&xs[(d << 6) + (tr << 2) + 32];
        const float4 b0 = cbT4[(d << 7) + tc];        // k = 0*128 + tc*4 ..
        const float4 b1 = cbT4[(d << 7) + 32 + tc];   // k = 128 + tc*4 ..
        const float4 b2 = cbT4[(d << 7) + 64 + tc];   // k = 256 + tc*4 ..
        const float4 b3 = cbT4[(d << 7) + 96 + tc];   // k = 384 + tc*4 ..
        const float av[8] = {a0.x, a0.y, a0.z, a0.w, a1.x, a1.y, a1.z, a1.w};
        const float bv[16] = {b0.x, b0.y, b0.z, b0.w,
                              b1.x, b1.y, b1.z, b1.w,
                              b2.x, b2.y, b2.z, b2.w,
                              b3.x, b3.y, b3.z, b3.w};
        #pragma unroll
        for (int i = 0; i < 8; ++i)
            #pragma unroll
            for (int c = 0; c < 16; ++c)
                acc[i][c] = fmaf(av[i], bv[c], acc[i][c]);
    }

    __syncthreads();   // sxx visible

    // ---- epilogue: ref-exact fp32 dist; per-row argmin + softmax(-dist) ----
    float* ip  = out + OFF_IP;
    float* enc = out + OFF_ENC;
    float invz[8];

    #pragma unroll
    for (int i = 0; i < 8; ++i) {
        const int row = ((i >> 2) << 5) + (tr << 2) + (i & 3);
        const float xxr = sxx[row];
        float m = 1e30f; int bk = 0;
        #pragma unroll
        for (int c = 0; c < 16; ++c) {
            const int k = ((c >> 2) << 7) + (tc << 2) + (c & 3);   // ascending in c
            const float t1   = xxr + ce2[k];          // fp32 round @ ulp(~64)
            const float dist = t1 - 2.f * acc[i][c];  // fp32 round @ ulp(~64)
            acc[i][c] = dist;
            if (dist < m) { m = dist; bk = k; }       // strict <: lowest k kept
        }
        // lexicographic (min dist, min k) butterfly across the 32 lanes of row
        #pragma unroll
        for (int off = 1; off < 32; off <<= 1) {
            const float mo = __shfl_xor(m, off, 32);
            const int   ko = __shfl_xor(bk, off, 32);
            if (mo < m || (mo == m && ko < bk)) { m = mo; bk = ko; }
        }
        float z = 0.f;
        #pragma unroll
        for (int c = 0; c < 16; ++c) {
            const float e = __expf(m - acc[i][c]);    // softmax(-dist), shifted
            acc[i][c] = e; z += e;
        }
        #pragma unroll
        for (int off = 1; off < 32; off <<= 1) z += __shfl_xor(z, off, 32);
        invz[i] = 1.f / z;

        if (tc == 0) {
            atomicAdd(&ip[((size_t)b << 9) + bk], 1.0f);
            enc[((size_t)b << 10) + row0 + row] = (float)bk;
        }
    }

    __syncthreads();

    // ---- softmax histogram: block-reduce in LDS, then global ----
    float* sh = out + OFF_SH;
    shist[t] = 0.f; shist[t + 256] = 0.f;
    __syncthreads();
    #pragma unroll
    for (int c = 0; c < 16; ++c) {
        const int k = ((c >> 2) << 7) + (tc << 2) + (c & 3);
        float cs = 0.f;
        #pragma unroll
        for (int i = 0; i < 8; ++i) cs += acc[i][c] * invz[i];
        atomicAdd(&shist[k], cs);
    }
    __syncthreads();
    atomicAdd(&sh[((size_t)b << 9) + t], shist[t]);
    atomicAdd(&sh[((size_t)b << 9) + t + 256], shist[t + 256]);
}

// ---- quant_out + loss (HBM-bound; reads enc, re-reads x coalesced) ----
__global__ __launch_bounds__(256) void vq_quant(
    const float* __restrict__ x, const float* __restrict__ cb,
    float* __restrict__ out)
{
    __shared__ int sidx[64];
    const int t    = threadIdx.x;
    const int blk  = blockIdx.x;
    const int b    = blk >> 4;
    const int row0 = (blk & 15) << 6;

    if (t < 64) sidx[t] = (int)out[OFF_ENC + ((size_t)b << 10) + row0 + t];
    __syncthreads();

    const int r = t & 63;
    const int code = sidx[r];
    const float* xb = x + ((size_t)b << 16) + row0;
    float lsum = 0.f;
    #pragma unroll
    for (int p = 0; p < 16; ++p) {
        const int d = (p << 2) + (t >> 6);
        const float q = cb[(code << 6) + d];
        const float diff = q - xb[((size_t)d << 10) + r];
        lsum += diff * diff;
        out[(((size_t)(b << 6) + d) << 10) + row0 + r] = q;
    }
    #pragma unroll
    for (int off = 1; off < 64; off <<= 1) lsum += __shfl_xor(lsum, off, 64);
    if ((t & 63) == 0) atomicAdd(&out[OFF_LOSS], lsum);
}

// loss scale + perplexity from per-batch code counts (512 threads, one k each)
__global__ __launch_bounds__(512) void vq_final(float* __restrict__ out)
{
    __shared__ float red[8];
    const int t = threadIdx.x;
    const float* ip = out + OFF_IP;
    float c0 = 0.f, c1 = 0.f, c2 = 0.f, c3 = 0.f;
    #pragma unroll
    for (int bb = 0; bb < 64; bb += 4) {
        c0 += ip[((bb + 0) << 9) + t];
        c1 += ip[((bb + 1) << 9) + t];
        c2 += ip[((bb + 2) << 9) + t];
        c3 += ip[((bb + 3) << 9) + t];
    }
    const float c = (c0 + c1) + (c2 + c3);
    const float pav = c * (1.0f / 65536.f);
    float h = pav * logf(pav + 1e-10f);
    #pragma unroll
    for (int off = 1; off < 64; off <<= 1) h += __shfl_xor(h, off, 64);
    if ((t & 63) == 0) red[t >> 6] = h;
    __syncthreads();
    if (t == 0) {
        float H = 0.f;
        #pragma unroll
        for (int w = 0; w < 8; ++w) H += red[w];
        out[OFF_PERP] = expf(-H);
        out[OFF_LOSS] = out[OFF_LOSS] * (1.25f / 4194304.f);
    }
}

extern "C" void kernel_launch(void* const* d_in, const int* in_sizes, int n_in,
                              void* d_out, int out_size, void* d_ws, size_t ws_size,
                              hipStream_t stream)
{
    const float* x  = (const float*)d_in[0];
    const float* cb = (const float*)d_in[1];
    float* out = (float*)d_out;
    float* cbT = (float*)d_ws;   // 128 KB (R4 demonstrated >=135 KB usable)

    // single memset: zero [loss, perp, enc, ip, sh] tail (enc overwritten anyway)
    hipMemsetAsync(out + OFF_LOSS, 0, (size_t)131074 * sizeof(float), stream);

    vq_prep<<<512, 64, 0, stream>>>(cb, cbT);
    vq_gemm<<<1024, 256, 0, stream>>>(x, cb, cbT, out);
    vq_quant<<<1024, 256, 0, stream>>>(x, cb, out);
    vq_final<<<1, 512, 0, stream>>>(out);
}

// Round 12
// 219.359 us; speedup vs baseline: 1.2420x; 1.1148x over previous
//
#include <hip/hip_runtime.h>

// Problem constants (fixed by setup_inputs):
//   x: [B=64, D=64, H=32, W=32] fp32   -> N = B*H*W = 65536 rows of D=64
//   codebook: [K=512, D=64] fp32
// Output layout (all fp32, concatenated flat in return order):
//   [0 .. 4194304)        quant_out [B,D,H,W]
//   [4194304]             loss
//   [4194305]             perplexity
//   [4194306 .. +65536)   encoding_indice [B, H*W] (as float)
//   [4259842 .. +32768)   index_program [B,K]
//   [4292610 .. +32768)   softmax_histogram [B,K]

#define OFF_LOSS 4194304
#define OFF_PERP 4194305
#define OFF_ENC  4194306
#define OFF_IP   4259842
#define OFF_SH   4292610

// Scores replicate the reference's fp32 expansion exactly (R6-proven):
//   t1   = fl32( ||x_r||^2 + ||e_k||^2 );  dist = fl32( t1 - 2*dot )
// argmin with lowest-k tie-break. All fmaf chains source-verbatim R6.
//
// R12: R11's global-B d-loop (126us, conflicts ~0.1M) plus:
//  1) quant+loss epilogue merged back into vq_gemm (R11's split was based on
//     a phantom race — vq_quant never touched d_ws; the split cost a
//     dispatch gap + 16.7MB x re-read).
//  2) B software prefetch: d+1's four float4s load during d's 128 FMAs
//     (~200cyc L1/L2 latency hidden; VGPR 96->~120, still <=128 so
//     4 waves/SIMD preserved).

// ---- prep: cbT[d][k] = cb[k][d] (128 KB in d_ws) ----
__global__ __launch_bounds__(64) void vq_prep(const float* __restrict__ cb,
                                              float* __restrict__ cbT)
{
    const int k = blockIdx.x;        // 0..511
    const int d = threadIdx.x;       // 0..63
    cbT[(d << 9) + k] = cb[(k << 6) + d];
}

// ---- gemm + argmin + softmax + enc/ip/sh + quant/loss ----
__global__ __launch_bounds__(256) void vq_gemm(
    const float* __restrict__ x, const float* __restrict__ cb,
    const float* __restrict__ cbT, float* __restrict__ out)
{
    __shared__ float xs[64 * 64];      // xs[d*64 + r], transposed x tile
    __shared__ float ce2[512];         // ||e_k||^2 (fp32)
    __shared__ float sxx[64];          // ||x_r||^2 (fp32) per row
    __shared__ float shist[512];       // softmax-histogram block reduce
    __shared__ int   sidx[64];         // argmin code per row

    const int t    = threadIdx.x;
    const int blk  = blockIdx.x;
    const int b    = blk >> 4;          // batch index
    const int row0 = (blk & 15) << 6;   // row offset within batch (H*W space)
    const int tr   = t >> 5;            // 0..7  (row group)
    const int tc   = t & 31;            // 0..31 (col group)

    const float4* cb4  = (const float4*)cb;
    const float4* cbT4 = (const float4*)cbT;

    // ---- stage x tile (coalesced: lanes sweep r for fixed d) ----
    {
        const float* xb = x + ((size_t)b << 16) + row0;   // b*D*HW
        #pragma unroll
        for (int p = 0; p < 16; ++p) {
            const int d = (p << 2) + (t >> 6);
            const int r = t & 63;
            xs[(d << 6) + r] = xb[((size_t)d << 10) + r];
        }
    }

    // ---- ce2: verbatim R6 arithmetic (expr + 16-lane xor tree) ----
    #pragma unroll
    for (int kc = 0; kc < 4; ++kc) {
        #pragma unroll
        for (int p = 0; p < 8; ++p) {
            const int fi = (p << 8) + t;      // float4 index in chunk, 0..2047
            const int k  = fi >> 4;           // 0..127
            const float4 v = cb4[(kc << 11) + fi];   // coalesced
            float pr = v.x * v.x + v.y * v.y + v.z * v.z + v.w * v.w;
            #pragma unroll
            for (int off = 1; off < 16; off <<= 1) pr += __shfl_xor(pr, off, 16);
            if ((t & 15) == 0) ce2[(kc << 7) + k] = pr;
        }
    }

    __syncthreads();   // xs + ce2 visible

    // ---- ||x_r||^2 fp32, sequential fmaf over d (verbatim R6) ----
    if (t < 64) {
        float s = 0.f;
        for (int d = 0; d < 64; ++d) { const float v = xs[(d << 6) + t]; s = fmaf(v, v, s); }
        sxx[t] = s;
    }

    float acc[8][16];
    #pragma unroll
    for (int i = 0; i < 8; ++i)
        #pragma unroll
        for (int c = 0; c < 16; ++c) acc[i][c] = 0.f;

    // ---- K-loop: A from LDS, B from global cbT (L1-hot) with software
    //      prefetch of d+1. Chain per acc[i][c]: ascending d, fmaf —
    //      bit-identical to R6. ----
    float4 nb0 = cbT4[tc];
    float4 nb1 = cbT4[32 + tc];
    float4 nb2 = cbT4[64 + tc];
    float4 nb3 = cbT4[96 + tc];
    #pragma unroll 1
    for (int d = 0; d < 64; ++d) {
        const float4 b0 = nb0, b1 = nb1, b2 = nb2, b3 = nb3;
        const int dn = ((d + 1) & 63) << 7;
        nb0 = cbT4[dn + tc];
        nb1 = cbT4[dn + 32 + tc];
        nb2 = cbT4[dn + 64 + tc];
        nb3 = cbT4[dn + 96 + tc];
        const float4 a0 = *(const float4*)&xs[(d << 6) + (tr << 2)];
        const float4 a1 = *(const float4*)&xs[(d << 6) + (tr << 2) + 32];
        const float av[8] = {a0.x, a0.y, a0.z, a0.w, a1.x, a1.y, a1.z, a1.w};
        const float bv[16] = {b0.x, b0.y, b0.z, b0.w,
                              b1.x, b1.y, b1.z, b1.w,
                              b2.x, b2.y, b2.z, b2.w,
                              b3.x, b3.y, b3.z, b3.w};
        #pragma unroll
        for (int i = 0; i < 8; ++i)
            #pragma unroll
            for (int c = 0; c < 16; ++c)
                acc[i][c] = fmaf(av[i], bv[c], acc[i][c]);
    }

    __syncthreads();   // sxx visible

    // ---- epilogue: ref-exact fp32 dist; per-row argmin + softmax(-dist) ----
    float* ip  = out + OFF_IP;
    float* enc = out + OFF_ENC;
    float invz[8];

    #pragma unroll
    for (int i = 0; i < 8; ++i) {
        const int row = ((i >> 2) << 5) + (tr << 2) + (i & 3);
        const float xxr = sxx[row];
        float m = 1e30f; int bk = 0;
        #pragma unroll
        for (int c = 0; c < 16; ++c) {
            const int k = ((c >> 2) << 7) + (tc << 2) + (c & 3);   // ascending in c
            const float t1   = xxr + ce2[k];          // fp32 round @ ulp(~64)
            const float dist = t1 - 2.f * acc[i][c];  // fp32 round @ ulp(~64)
            acc[i][c] = dist;
            if (dist < m) { m = dist; bk = k; }       // strict <: lowest k kept
        }
        // lexicographic (min dist, min k) butterfly across the 32 lanes of row
        #pragma unroll
        for (int off = 1; off < 32; off <<= 1) {
            const float mo = __shfl_xor(m, off, 32);
            const int   ko = __shfl_xor(bk, off, 32);
            if (mo < m || (mo == m && ko < bk)) { m = mo; bk = ko; }
        }
        float z = 0.f;
        #pragma unroll
        for (int c = 0; c < 16; ++c) {
            const float e = __expf(m - acc[i][c]);    // softmax(-dist), shifted
            acc[i][c] = e; z += e;
        }
        #pragma unroll
        for (int off = 1; off < 32; off <<= 1) z += __shfl_xor(z, off, 32);
        invz[i] = 1.f / z;

        if (tc == 0) {
            sidx[row] = bk;
            atomicAdd(&ip[((size_t)b << 9) + bk], 1.0f);
            enc[((size_t)b << 10) + row0 + row] = (float)bk;
        }
    }

    __syncthreads();   // sidx visible

    // ---- softmax histogram: block-reduce in LDS, then global ----
    float* sh = out + OFF_SH;
    shist[t] = 0.f; shist[t + 256] = 0.f;
    __syncthreads();
    #pragma unroll
    for (int c = 0; c < 16; ++c) {
        const int k = ((c >> 2) << 7) + (tc << 2) + (c & 3);
        float cs = 0.f;
        #pragma unroll
        for (int i = 0; i < 8; ++i) cs += acc[i][c] * invz[i];
        atomicAdd(&shist[k], cs);
    }
    __syncthreads();
    atomicAdd(&sh[((size_t)b << 9) + t], shist[t]);
    atomicAdd(&sh[((size_t)b << 9) + t + 256], shist[t + 256]);

    // ---- quantized output + loss partial (from sidx; xs still resident) ----
    const int r = t & 63;
    const int code = sidx[r];
    float lsum = 0.f;
    #pragma unroll
    for (int p = 0; p < 16; ++p) {
        const int d = (p << 2) + (t >> 6);
        const float q = cb[(code << 6) + d];
        const float diff = q - xs[(d << 6) + r];
        lsum += diff * diff;
        out[(((size_t)(b << 6) + d) << 10) + row0 + r] = q;
    }
    #pragma unroll
    for (int off = 1; off < 64; off <<= 1) lsum += __shfl_xor(lsum, off, 64);
    if ((t & 63) == 0) atomicAdd(&out[OFF_LOSS], lsum);
}

// loss scale + perplexity from per-batch code counts (512 threads, one k each)
__global__ __launch_bounds__(512) void vq_final(float* __restrict__ out)
{
    __shared__ float red[8];
    const int t = threadIdx.x;
    const float* ip = out + OFF_IP;
    float c0 = 0.f, c1 = 0.f, c2 = 0.f, c3 = 0.f;
    #pragma unroll
    for (int bb = 0; bb < 64; bb += 4) {
        c0 += ip[((bb + 0) << 9) + t];
        c1 += ip[((bb + 1) << 9) + t];
        c2 += ip[((bb + 2) << 9) + t];
        c3 += ip[((bb + 3) << 9) + t];
    }
    const float c = (c0 + c1) + (c2 + c3);
    const float pav = c * (1.0f / 65536.f);
    float h = pav * logf(pav + 1e-10f);
    #pragma unroll
    for (int off = 1; off < 64; off <<= 1) h += __shfl_xor(h, off, 64);
    if ((t & 63) == 0) red[t >> 6] = h;
    __syncthreads();
    if (t == 0) {
        float H = 0.f;
        #pragma unroll
        for (int w = 0; w < 8; ++w) H += red[w];
        out[OFF_PERP] = expf(-H);
        out[OFF_LOSS] = out[OFF_LOSS] * (1.25f / 4194304.f);
    }
}

extern "C" void kernel_launch(void* const* d_in, const int* in_sizes, int n_in,
                              void* d_out, int out_size, void* d_ws, size_t ws_size,
                              hipStream_t stream)
{
    const float* x  = (const float*)d_in[0];
    const float* cb = (const float*)d_in[1];
    float* out = (float*)d_out;
    float* cbT = (float*)d_ws;   // 128 KB

    // single memset: zero [loss, perp, enc, ip, sh] tail (enc overwritten anyway)
    hipMemsetAsync(out + OFF_LOSS, 0, (size_t)131074 * sizeof(float), stream);

    vq_prep<<<512, 64, 0, stream>>>(cb, cbT);
    vq_gemm<<<1024, 256, 0, stream>>>(x, cb, cbT, out);
    vq_final<<<1, 512, 0, stream>>>(out);
}